// Round 2
// baseline (288.920 us; speedup 1.0000x reference)
//
#include <hip/hip_runtime.h>
#include <math.h>

#define BB    2
#define NN    1024
#define CSD   384
#define CZD   128
#define CHD   16
#define HH    12
#define PQD   4
#define PVD   8
#define KNB   50
#define HALFN 512
#define MTOK  (BB*NN)
#define LINW  1152
#define CATW  2112

// ---------------- generic tiled GEMM: C = A @ W^T + bias ----------------
// A: (M, Kdim) row-major, W: (Nout, Kdim) row-major, C: (M, Nout).
// Grid (M/64, Nout/64), 256 threads, 4x4 micro-tile per thread.
__global__ __launch_bounds__(256) void gemm_wt(
    const float* __restrict__ A, const float* __restrict__ W,
    const float* __restrict__ bias, float* __restrict__ C,
    int Kdim, int Nout)
{
    __shared__ float As[16][68];
    __shared__ float Bs[16][68];
    const int tid = threadIdx.x;
    const int tm = tid >> 4, tn = tid & 15;
    const int rowBase = blockIdx.x * 64, colBase = blockIdx.y * 64;
    const int lm = tid >> 2;          // 0..63
    const int lk = (tid & 3) << 2;    // 0,4,8,12
    const float* aRow = A + (size_t)(rowBase + lm) * Kdim;
    const float* wRow = W + (size_t)(colBase + lm) * Kdim;
    float acc[4][4] = {};
    for (int k0 = 0; k0 < Kdim; k0 += 16) {
        float4 av = *(const float4*)(aRow + k0 + lk);
        float4 bv = *(const float4*)(wRow + k0 + lk);
        __syncthreads();
        As[lk+0][lm] = av.x; As[lk+1][lm] = av.y; As[lk+2][lm] = av.z; As[lk+3][lm] = av.w;
        Bs[lk+0][lm] = bv.x; Bs[lk+1][lm] = bv.y; Bs[lk+2][lm] = bv.z; Bs[lk+3][lm] = bv.w;
        __syncthreads();
        #pragma unroll
        for (int kk = 0; kk < 16; ++kk) {
            float4 a4 = *(const float4*)&As[kk][tm*4];
            float4 b4 = *(const float4*)&Bs[kk][tn*4];
            float ar[4] = {a4.x, a4.y, a4.z, a4.w};
            float br[4] = {b4.x, b4.y, b4.z, b4.w};
            #pragma unroll
            for (int i = 0; i < 4; ++i)
                #pragma unroll
                for (int j = 0; j < 4; ++j)
                    acc[i][j] += ar[i] * br[j];
        }
    }
    const int c0 = colBase + tn*4;
    float b0 = bias[c0+0], b1 = bias[c0+1], b2 = bias[c0+2], b3 = bias[c0+3];
    #pragma unroll
    for (int i = 0; i < 4; ++i) {
        int r = rowBase + tm*4 + i;
        float4 o;
        o.x = acc[i][0] + b0; o.y = acc[i][1] + b1;
        o.z = acc[i][2] + b2; o.w = acc[i][3] + b3;
        *(float4*)(C + (size_t)r * Nout + c0) = o;
    }
}

// ------------- projection GEMM: 4 weight segments into lin (M,1152) -------------
// cols [0,192)=Wq, [192,576)=Wkv, [576,720)=Wqp, [720,1152)=Wkvp
__global__ __launch_bounds__(256) void proj_gemm(
    const float* __restrict__ A,
    const float* __restrict__ Wq,  const float* __restrict__ bq,
    const float* __restrict__ Wkv, const float* __restrict__ bkv,
    const float* __restrict__ Wqp, const float* __restrict__ bqp,
    const float* __restrict__ Wkvp,const float* __restrict__ bkvp,
    float* __restrict__ lin)
{
    __shared__ float As[16][68];
    __shared__ float Bs[16][68];
    const int tid = threadIdx.x;
    const int tm = tid >> 4, tn = tid & 15;
    const int rowBase = blockIdx.x * 64, colBase = blockIdx.y * 64;
    const int lm = tid >> 2;
    const int lk = (tid & 3) << 2;
    const float* aRow = A + (size_t)(rowBase + lm) * CSD;
    int gn = colBase + lm;
    const float* Wp; int wr;
    if      (gn < 192) { Wp = Wq;   wr = gn;       }
    else if (gn < 576) { Wp = Wkv;  wr = gn - 192; }
    else if (gn < 720) { Wp = Wqp;  wr = gn - 576; }
    else               { Wp = Wkvp; wr = gn - 720; }
    const float* wRow = Wp + (size_t)wr * CSD;
    float acc[4][4] = {};
    for (int k0 = 0; k0 < CSD; k0 += 16) {
        float4 av = *(const float4*)(aRow + k0 + lk);
        float4 bv = *(const float4*)(wRow + k0 + lk);
        __syncthreads();
        As[lk+0][lm] = av.x; As[lk+1][lm] = av.y; As[lk+2][lm] = av.z; As[lk+3][lm] = av.w;
        Bs[lk+0][lm] = bv.x; Bs[lk+1][lm] = bv.y; Bs[lk+2][lm] = bv.z; Bs[lk+3][lm] = bv.w;
        __syncthreads();
        #pragma unroll
        for (int kk = 0; kk < 16; ++kk) {
            float4 a4 = *(const float4*)&As[kk][tm*4];
            float4 b4 = *(const float4*)&Bs[kk][tn*4];
            float ar[4] = {a4.x, a4.y, a4.z, a4.w};
            float br[4] = {b4.x, b4.y, b4.z, b4.w};
            #pragma unroll
            for (int i = 0; i < 4; ++i)
                #pragma unroll
                for (int j = 0; j < 4; ++j)
                    acc[i][j] += ar[i] * br[j];
        }
    }
    float bia[4];
    #pragma unroll
    for (int j = 0; j < 4; ++j) {
        int c = colBase + tn*4 + j;
        if      (c < 192) bia[j] = bq[c];
        else if (c < 576) bia[j] = bkv[c-192];
        else if (c < 720) bia[j] = bqp[c-576];
        else              bia[j] = bkvp[c-720];
    }
    #pragma unroll
    for (int i = 0; i < 4; ++i) {
        int r = rowBase + tm*4 + i;
        float4 o;
        o.x = acc[i][0] + bia[0]; o.y = acc[i][1] + bia[1];
        o.z = acc[i][2] + bia[2]; o.w = acc[i][3] + bia[3];
        *(float4*)(lin + (size_t)r * LINW + colBase + tn*4) = o;
    }
}

// ------------- point transform: rot @ p + trans -------------
// lin qp segment: (3, 48) at +576   -> q_pts (M,H,PQ,3)
// lin kvp segment: (3, 144) at +720 -> k_pts (M,H,PQ,3), v_pts (M,H,PV,3)
// 192 threads: j<48 = q point j; j>=48 -> kv point j-48 (h=j2/12, pp=j2%12)
__global__ void point_transform(const float* __restrict__ lin,
                                const float* __restrict__ rot,
                                const float* __restrict__ trans,
                                float* __restrict__ q_pts,
                                float* __restrict__ k_pts,
                                float* __restrict__ v_pts)
{
    const int m = blockIdx.x;
    const int j = threadIdx.x;   // 0..191
    const float* R = rot + (size_t)m * 9;
    const float* T = trans + (size_t)m * 3;
    const float* L = lin + (size_t)m * LINW;
    float p0, p1, p2;
    if (j < 48) {
        p0 = L[576 + j]; p1 = L[576 + 48 + j]; p2 = L[576 + 96 + j];
    } else {
        int j2 = j - 48;                     // 0..143
        p0 = L[720 + j2]; p1 = L[720 + 144 + j2]; p2 = L[720 + 288 + j2];
    }
    float ox = R[0]*p0 + R[1]*p1 + R[2]*p2 + T[0];
    float oy = R[3]*p0 + R[4]*p1 + R[5]*p2 + T[1];
    float oz = R[6]*p0 + R[7]*p1 + R[8]*p2 + T[2];
    if (j < 48) {
        float* o = q_pts + (size_t)m * 144 + 3 * j;
        o[0] = ox; o[1] = oy; o[2] = oz;
    } else {
        int j2 = j - 48, h = j2 / 12, pp = j2 % 12;
        if (pp < PQD) {
            float* o = k_pts + (size_t)m * 144 + ((h*PQD + pp) * 3);
            o[0] = ox; o[1] = oy; o[2] = oz;
        } else {
            float* o = v_pts + (size_t)m * 288 + ((h*PVD + pp - PQD) * 3);
            o[0] = ox; o[1] = oy; o[2] = oz;
        }
    }
}

// ------------- top-K neighbors by distance (bitonic sort of 1024 keys) -------------
__global__ __launch_bounds__(256) void topk_kernel(const float* __restrict__ trans,
                                                   int* __restrict__ nidx)
{
    __shared__ float t3[3 * NN];
    __shared__ unsigned long long keys[NN];
    const int m = blockIdx.x, b = m / NN, n = m % NN, tid = threadIdx.x;
    for (int i = tid; i < 3 * NN; i += 256) t3[i] = trans[(size_t)b * 3 * NN + i];
    __syncthreads();
    const float tx = t3[n*3], ty = t3[n*3+1], tz = t3[n*3+2];
    for (int j = tid; j < NN; j += 256) {
        float dx = tx - t3[j*3], dy = ty - t3[j*3+1], dz = tz - t3[j*3+2];
        float d = sqrtf(dx*dx + dy*dy + dz*dz);
        keys[j] = ((unsigned long long)__float_as_uint(d) << 32) | (unsigned)j;
    }
    for (int k2 = 2; k2 <= NN; k2 <<= 1) {
        for (int j2 = k2 >> 1; j2 > 0; j2 >>= 1) {
            __syncthreads();
            for (int i = tid; i < NN; i += 256) {
                int ixj = i ^ j2;
                if (ixj > i) {
                    unsigned long long a = keys[i], c = keys[ixj];
                    bool up = ((i & k2) == 0);
                    if ((a > c) == up) { keys[i] = c; keys[ixj] = a; }
                }
            }
        }
    }
    __syncthreads();
    if (tid < KNB) nidx[(size_t)m * KNB + tid] = (int)(keys[tid] & 0xffffffffu);
}

// ------------- attention per token -------------
__global__ __launch_bounds__(256) void attn_kernel(
    const float* __restrict__ lin,     // q at +0, kv at +192 (per 1152-row)
    const float* __restrict__ q_pts,
    const float* __restrict__ k_pts,
    const float* __restrict__ v_pts,
    const int*   __restrict__ nidx,
    const float* __restrict__ z,       // (B, 512, 512, 128)
    const float* __restrict__ Wb,      // (12, 128)
    const float* __restrict__ bbv,     // (12)
    const float* __restrict__ hwin,    // (12)
    const float* __restrict__ mask,    // (B, N)
    const float* __restrict__ rot,
    const float* __restrict__ trans,
    float* __restrict__ cat)           // (M, 2112)
{
    __shared__ float zn[KNB][CZD];     // 25.6 KB
    __shared__ float aP[HH][KNB + 2];
    __shared__ float qloc[192];
    __shared__ float qp[144];
    __shared__ float WbS[HH][CZD];     // 6 KB
    __shared__ int   nk[KNB];
    __shared__ float maskn[KNB];
    __shared__ float hwS[HH];
    __shared__ float opt[288];

    const int m = blockIdx.x;
    const int b = m / NN, n = m % NN;
    const int tid = threadIdx.x;

    if (tid < KNB) nk[tid] = nidx[(size_t)m * KNB + tid];
    __syncthreads();

    for (int i = tid; i < HH * CZD; i += 256) WbS[i / CZD][i % CZD] = Wb[i];
    for (int i = tid; i < 192; i += 256) qloc[i] = lin[(size_t)m * LINW + i];
    for (int i = tid; i < 144; i += 256) qp[i] = q_pts[(size_t)m * 144 + i];
    if (tid < HH) hwS[tid] = log1pf(expf(hwin[tid])) * 0.13608276348795434f; // sqrt(1/54)
    if (tid < KNB) maskn[tid] = 100000.0f * (mask[m] * mask[(size_t)b * NN + nk[tid]] - 1.0f);
    {
        int wid = tid >> 6, lane = tid & 63;
        for (int k = wid; k < KNB; k += 4) {
            const float* zr = z + (((size_t)b * HALFN + (n & (HALFN-1))) * HALFN + (nk[k] & (HALFN-1))) * CZD;
            float2 v2 = *(const float2*)(zr + lane * 2);
            *(float2*)&zn[k][lane * 2] = v2;
        }
    }
    __syncthreads();

    // logits
    for (int idx = tid; idx < HH * KNB; idx += 256) {
        int k = idx / HH, h = idx % HH;
        int mk = b * NN + nk[k];
        const float* kvr = lin + (size_t)mk * LINW + 192 + h * 32;
        float qk = 0.f;
        #pragma unroll
        for (int c = 0; c < CHD; ++c) qk += qloc[h*16 + c] * kvr[c];
        const float* kpr = k_pts + (size_t)mk * 144 + h * 12;
        float d2s = 0.f;
        #pragma unroll
        for (int p = 0; p < PQD; ++p) {
            float dx = qp[h*12 + p*3 + 0] - kpr[p*3 + 0];
            float dy = qp[h*12 + p*3 + 1] - kpr[p*3 + 1];
            float dz = qp[h*12 + p*3 + 2] - kpr[p*3 + 2];
            d2s += dx*dx + dy*dy + dz*dz;
        }
        float bp = bbv[h];
        for (int c = 0; c < CZD; ++c) bp += zn[k][c] * WbS[h][c];
        aP[h][k] = qk * 0.14433756729740643f      // sqrt(1/(3*16))
                 + 0.5773502691896258f * bp       // sqrt(1/3)
                 - 0.5f * hwS[h] * d2s
                 + maskn[k];
    }
    __syncthreads();

    // softmax over k per head (wave-parallel, lanes 0..49 hold values)
    {
        int wid = tid >> 6, lane = tid & 63;
        for (int h = wid; h < HH; h += 4) {
            float v = (lane < KNB) ? aP[h][lane] : -1e30f;
            float mx = v;
            #pragma unroll
            for (int off = 32; off; off >>= 1) mx = fmaxf(mx, __shfl_xor(mx, off));
            float e = (lane < KNB) ? expf(v - mx) : 0.f;
            float s = e;
            #pragma unroll
            for (int off = 32; off; off >>= 1) s += __shfl_xor(s, off);
            if (lane < KNB) aP[h][lane] = e / s;
        }
    }
    __syncthreads();

    // o (192) and o_pt raw (288)
    for (int idx = tid; idx < 480; idx += 256) {
        float s = 0.f;
        if (idx < 192) {
            int h = idx >> 4, c = idx & 15;
            for (int k = 0; k < KNB; ++k) {
                int mk = b * NN + nk[k];
                s += aP[h][k] * lin[(size_t)mk * LINW + 192 + h*32 + 16 + c];
            }
            cat[(size_t)m * CATW + idx] = s;
        } else {
            int j = idx - 192;
            int h = j / 24, r = j % 24;
            for (int k = 0; k < KNB; ++k) {
                int mk = b * NN + nk[k];
                s += aP[h][k] * v_pts[(size_t)mk * 288 + h*24 + r];
            }
            opt[j] = s;
        }
    }
    __syncthreads();

    // inverse frame transform + norm
    if (tid < 96) {
        int hp = tid;
        float x = opt[hp*3+0] - trans[(size_t)m*3+0];
        float y = opt[hp*3+1] - trans[(size_t)m*3+1];
        float z0 = opt[hp*3+2] - trans[(size_t)m*3+2];
        const float* R = rot + (size_t)m * 9;
        float o0 = R[0]*x + R[3]*y + R[6]*z0;   // rot^T
        float o1 = R[1]*x + R[4]*y + R[7]*z0;
        float o2 = R[2]*x + R[5]*y + R[8]*z0;
        float nrm = sqrtf(o0*o0 + o1*o1 + o2*o2 + 1e-8f);
        float* c0 = cat + (size_t)m * CATW;
        c0[192 + hp] = o0;
        c0[288 + hp] = o1;
        c0[384 + hp] = o2;
        c0[480 + hp] = nrm;
    }

    // o_pair (1536) from LDS zn
    for (int idx = tid; idx < HH * CZD; idx += 256) {
        int h = idx >> 7, c = idx & 127;
        float s = 0.f;
        for (int k = 0; k < KNB; ++k) s += aP[h][k] * zn[k][c];
        cat[(size_t)m * CATW + 576 + idx] = s;
    }
}

extern "C" void kernel_launch(void* const* d_in, const int* in_sizes, int n_in,
                              void* d_out, int out_size, void* d_ws, size_t ws_size,
                              hipStream_t stream) {
    const float* s     = (const float*)d_in[0];
    const float* z     = (const float*)d_in[1];
    const float* rot   = (const float*)d_in[2];
    const float* trans = (const float*)d_in[3];
    const float* mask  = (const float*)d_in[4];
    // d_in[5] rel_pos unused
    const float* Wq    = (const float*)d_in[6];
    const float* bq    = (const float*)d_in[7];
    const float* Wkv   = (const float*)d_in[8];
    const float* bkv   = (const float*)d_in[9];
    const float* Wqp   = (const float*)d_in[10];
    const float* bqp   = (const float*)d_in[11];
    const float* Wkvp  = (const float*)d_in[12];
    const float* bkvp  = (const float*)d_in[13];
    const float* Wb    = (const float*)d_in[14];
    const float* bb    = (const float*)d_in[15];
    const float* hw    = (const float*)d_in[16];
    const float* Wout  = (const float*)d_in[17];
    const float* bout  = (const float*)d_in[18];
    float* out = (float*)d_out;

    float* ws    = (float*)d_ws;
    float* lin   = ws;                              // 2048*1152
    float* qpts  = lin  + (size_t)MTOK * LINW;      // 2048*144
    float* kpts  = qpts + (size_t)MTOK * 144;       // 2048*144
    float* vpts  = kpts + (size_t)MTOK * 144;       // 2048*288
    int*   nidxb = (int*)(vpts + (size_t)MTOK * 288);
    float* cat   = (float*)(nidxb + (size_t)MTOK * KNB); // 2048*2112

    dim3 g1(MTOK / 64, LINW / 64);
    proj_gemm<<<g1, 256, 0, stream>>>(s, Wq, bq, Wkv, bkv, Wqp, bqp, Wkvp, bkvp, lin);
    point_transform<<<MTOK, 192, 0, stream>>>(lin, rot, trans, qpts, kpts, vpts);
    topk_kernel<<<MTOK, 256, 0, stream>>>(trans, nidxb);
    attn_kernel<<<MTOK, 256, 0, stream>>>(lin, qpts, kpts, vpts, nidxb, z, Wb, bb, hw,
                                          mask, rot, trans, cat);
    dim3 g2(MTOK / 64, 384 / 64);
    gemm_wt<<<g2, 256, 0, stream>>>(cat, Wout, bout, out, CATW, 384);
}

// Round 3
// 194.073 us; speedup vs baseline: 1.4887x; 1.4887x over previous
//
#include <hip/hip_runtime.h>
#include <math.h>

#define BB    2
#define NN    1024
#define CSD   384
#define CZD   128
#define CZP   132     // padded LDS row (bank spread)
#define CHD   16
#define HH    12
#define PQD   4
#define PVD   8
#define KNB   50
#define HALFN 512
#define MTOK  (BB*NN)
#define LINW  1152
#define CATW  2112
#define SPLITK 4

// ---------------- generic tiled GEMM: C = A @ W^T + bias ----------------
__global__ __launch_bounds__(256) void proj_gemm(
    const float* __restrict__ A,
    const float* __restrict__ Wq,  const float* __restrict__ bq,
    const float* __restrict__ Wkv, const float* __restrict__ bkv,
    const float* __restrict__ Wqp, const float* __restrict__ bqp,
    const float* __restrict__ Wkvp,const float* __restrict__ bkvp,
    float* __restrict__ lin)
{
    __shared__ float As[16][68];
    __shared__ float Bs[16][68];
    const int tid = threadIdx.x;
    const int tm = tid >> 4, tn = tid & 15;
    const int rowBase = blockIdx.x * 64, colBase = blockIdx.y * 64;
    const int lm = tid >> 2;
    const int lk = (tid & 3) << 2;
    const float* aRow = A + (size_t)(rowBase + lm) * CSD;
    int gn = colBase + lm;
    const float* Wp; int wr;
    if      (gn < 192) { Wp = Wq;   wr = gn;       }
    else if (gn < 576) { Wp = Wkv;  wr = gn - 192; }
    else if (gn < 720) { Wp = Wqp;  wr = gn - 576; }
    else               { Wp = Wkvp; wr = gn - 720; }
    const float* wRow = Wp + (size_t)wr * CSD;
    float acc[4][4] = {};
    for (int k0 = 0; k0 < CSD; k0 += 16) {
        float4 av = *(const float4*)(aRow + k0 + lk);
        float4 bv = *(const float4*)(wRow + k0 + lk);
        __syncthreads();
        As[lk+0][lm] = av.x; As[lk+1][lm] = av.y; As[lk+2][lm] = av.z; As[lk+3][lm] = av.w;
        Bs[lk+0][lm] = bv.x; Bs[lk+1][lm] = bv.y; Bs[lk+2][lm] = bv.z; Bs[lk+3][lm] = bv.w;
        __syncthreads();
        #pragma unroll
        for (int kk = 0; kk < 16; ++kk) {
            float4 a4 = *(const float4*)&As[kk][tm*4];
            float4 b4 = *(const float4*)&Bs[kk][tn*4];
            float ar[4] = {a4.x, a4.y, a4.z, a4.w};
            float br[4] = {b4.x, b4.y, b4.z, b4.w};
            #pragma unroll
            for (int i = 0; i < 4; ++i)
                #pragma unroll
                for (int j = 0; j < 4; ++j)
                    acc[i][j] += ar[i] * br[j];
        }
    }
    float bia[4];
    #pragma unroll
    for (int j = 0; j < 4; ++j) {
        int c = colBase + tn*4 + j;
        if      (c < 192) bia[j] = bq[c];
        else if (c < 576) bia[j] = bkv[c-192];
        else if (c < 720) bia[j] = bqp[c-576];
        else              bia[j] = bkvp[c-720];
    }
    #pragma unroll
    for (int i = 0; i < 4; ++i) {
        int r = rowBase + tm*4 + i;
        float4 o;
        o.x = acc[i][0] + bia[0]; o.y = acc[i][1] + bia[1];
        o.z = acc[i][2] + bia[2]; o.w = acc[i][3] + bia[3];
        *(float4*)(lin + (size_t)r * LINW + colBase + tn*4) = o;
    }
}

// ------------- split-K out-GEMM: parts[s] = A @ W^T over k-chunk s -------------
__global__ __launch_bounds__(256) void gemm_wt_splitk(
    const float* __restrict__ A, const float* __restrict__ W,
    float* __restrict__ parts, int Kdim, int Nout, int kchunk)
{
    __shared__ float As[16][68];
    __shared__ float Bs[16][68];
    const int tid = threadIdx.x;
    const int tm = tid >> 4, tn = tid & 15;
    const int rowBase = blockIdx.x * 64, colBase = blockIdx.y * 64;
    const int sk = blockIdx.z;
    const int k0s = sk * kchunk, k0e = k0s + kchunk;
    const int lm = tid >> 2;
    const int lk = (tid & 3) << 2;
    const float* aRow = A + (size_t)(rowBase + lm) * Kdim;
    const float* wRow = W + (size_t)(colBase + lm) * Kdim;
    float acc[4][4] = {};
    for (int k0 = k0s; k0 < k0e; k0 += 16) {
        float4 av = *(const float4*)(aRow + k0 + lk);
        float4 bv = *(const float4*)(wRow + k0 + lk);
        __syncthreads();
        As[lk+0][lm] = av.x; As[lk+1][lm] = av.y; As[lk+2][lm] = av.z; As[lk+3][lm] = av.w;
        Bs[lk+0][lm] = bv.x; Bs[lk+1][lm] = bv.y; Bs[lk+2][lm] = bv.z; Bs[lk+3][lm] = bv.w;
        __syncthreads();
        #pragma unroll
        for (int kk = 0; kk < 16; ++kk) {
            float4 a4 = *(const float4*)&As[kk][tm*4];
            float4 b4 = *(const float4*)&Bs[kk][tn*4];
            float ar[4] = {a4.x, a4.y, a4.z, a4.w};
            float br[4] = {b4.x, b4.y, b4.z, b4.w};
            #pragma unroll
            for (int i = 0; i < 4; ++i)
                #pragma unroll
                for (int j = 0; j < 4; ++j)
                    acc[i][j] += ar[i] * br[j];
        }
    }
    float* dst = parts + (size_t)sk * MTOK * Nout;
    const int c0 = colBase + tn*4;
    #pragma unroll
    for (int i = 0; i < 4; ++i) {
        int r = rowBase + tm*4 + i;
        float4 o;
        o.x = acc[i][0]; o.y = acc[i][1]; o.z = acc[i][2]; o.w = acc[i][3];
        *(float4*)(dst + (size_t)r * Nout + c0) = o;
    }
}

__global__ __launch_bounds__(256) void reduce_splitk(
    const float* __restrict__ parts, const float* __restrict__ bias,
    float* __restrict__ out)
{
    const int i4 = blockIdx.x * 256 + threadIdx.x;   // float4 index
    const int TOT4 = MTOK * 384 / 4;
    if (i4 >= TOT4) return;
    const int c4 = i4 % (384 / 4);
    float4 acc = *(const float4*)(bias + c4 * 4);
    #pragma unroll
    for (int s = 0; s < SPLITK; ++s) {
        float4 p = *(const float4*)(parts + (size_t)s * MTOK * 384 + (size_t)i4 * 4);
        acc.x += p.x; acc.y += p.y; acc.z += p.z; acc.w += p.w;
    }
    *(float4*)(out + (size_t)i4 * 4) = acc;
}

// ------------- point transform: rot @ p + trans -------------
__global__ void point_transform(const float* __restrict__ lin,
                                const float* __restrict__ rot,
                                const float* __restrict__ trans,
                                float* __restrict__ q_pts,
                                float* __restrict__ k_pts,
                                float* __restrict__ v_pts)
{
    const int m = blockIdx.x;
    const int j = threadIdx.x;   // 0..191
    const float* R = rot + (size_t)m * 9;
    const float* T = trans + (size_t)m * 3;
    const float* L = lin + (size_t)m * LINW;
    float p0, p1, p2;
    if (j < 48) {
        p0 = L[576 + j]; p1 = L[576 + 48 + j]; p2 = L[576 + 96 + j];
    } else {
        int j2 = j - 48;                     // 0..143
        p0 = L[720 + j2]; p1 = L[720 + 144 + j2]; p2 = L[720 + 288 + j2];
    }
    float ox = R[0]*p0 + R[1]*p1 + R[2]*p2 + T[0];
    float oy = R[3]*p0 + R[4]*p1 + R[5]*p2 + T[1];
    float oz = R[6]*p0 + R[7]*p1 + R[8]*p2 + T[2];
    if (j < 48) {
        float* o = q_pts + (size_t)m * 144 + 3 * j;
        o[0] = ox; o[1] = oy; o[2] = oz;
    } else {
        int j2 = j - 48, h = j2 / 12, pp = j2 % 12;
        if (pp < PQD) {
            float* o = k_pts + (size_t)m * 144 + ((h*PQD + pp) * 3);
            o[0] = ox; o[1] = oy; o[2] = oz;
        } else {
            float* o = v_pts + (size_t)m * 288 + ((h*PVD + pp - PQD) * 3);
            o[0] = ox; o[1] = oy; o[2] = oz;
        }
    }
}

// ------------- top-K neighbors via radix-select on packed (dist,idx) keys -------------
// Downstream k-contractions are order-invariant -> only the SET of top-50 matters.
__global__ __launch_bounds__(256) void topk_kernel(const float* __restrict__ trans,
                                                   int* __restrict__ nidx)
{
    __shared__ float t3[3 * NN];                 // 12 KB
    __shared__ unsigned long long keys[NN];      // 8 KB
    __shared__ unsigned int hist[256];
    __shared__ unsigned int warp_sums[4];
    __shared__ unsigned int s_seldig, s_selexc, s_selcnt, out_cnt;
    __shared__ unsigned long long s_pivot;
    __shared__ int s_done;

    const int m = blockIdx.x, b = m / NN, n = m % NN, tid = threadIdx.x;
    const int lane = tid & 63, wid = tid >> 6;

    if (tid == 0) { s_done = 0; out_cnt = 0; }
    for (int i = tid; i < 3 * NN; i += 256) t3[i] = trans[(size_t)b * 3 * NN + i];
    __syncthreads();
    const float tx = t3[n*3], ty = t3[n*3+1], tz = t3[n*3+2];
    for (int j = tid; j < NN; j += 256) {
        float dx = tx - t3[j*3], dy = ty - t3[j*3+1], dz = tz - t3[j*3+2];
        float d = sqrtf(dx*dx + dy*dy + dz*dz);
        keys[j] = ((unsigned long long)__float_as_uint(d) << 32) | (unsigned)j;
    }

    unsigned long long hi = 0;
    int rank = 0;
    const int target = KNB - 1;                  // 0-based rank of pivot
    for (int d = 7; d >= 0; --d) {
        __syncthreads();
        if (s_done) break;
        const int shift = d * 8;
        hist[tid] = 0;
        __syncthreads();
        for (int j = tid; j < NN; j += 256) {
            unsigned long long key = keys[j];
            bool match = (d == 7) || ((key >> (shift + 8)) == hi);
            if (match) atomicAdd(&hist[(unsigned)(key >> shift) & 0xffu], 1u);
        }
        __syncthreads();
        unsigned int v = hist[tid];
        unsigned int inc = v;
        #pragma unroll
        for (int off = 1; off < 64; off <<= 1) {
            unsigned int nv = __shfl_up(inc, off);
            if (lane >= off) inc += nv;
        }
        if (lane == 63) warp_sums[wid] = inc;
        __syncthreads();
        unsigned int woff = 0;
        for (int w = 0; w < wid; ++w) woff += warp_sums[w];
        unsigned int exc = woff + inc - v;
        int t = target - rank;
        if ((int)exc <= t && t < (int)(exc + v)) {
            s_seldig = (unsigned)tid; s_selexc = exc; s_selcnt = v;
        }
        __syncthreads();
        hi = (hi << 8) | (unsigned long long)s_seldig;
        rank += (int)s_selexc;
        if (s_selcnt == 1u) {
            for (int j = tid; j < NN; j += 256) {
                unsigned long long key = keys[j];
                if ((key >> shift) == hi) s_pivot = key;
            }
            if (tid == 0) s_done = 1;
        } else if (d == 0) {
            if (tid == 0) { s_pivot = hi; s_done = 1; }
        }
    }
    __syncthreads();
    const unsigned long long pivot = s_pivot;
    for (int j = tid; j < NN; j += 256) {
        unsigned long long key = keys[j];
        if (key <= pivot) {
            unsigned p = atomicAdd(&out_cnt, 1u);
            nidx[(size_t)m * KNB + p] = (int)(key & 0xffffffffu);
        }
    }
}

// ------------- attention per token -------------
__global__ __launch_bounds__(256) void attn_kernel(
    const float* __restrict__ lin,     // q at +0, kv at +192 (per 1152-row)
    const float* __restrict__ q_pts,
    const float* __restrict__ k_pts,
    const float* __restrict__ v_pts,
    const int*   __restrict__ nidx,
    const float* __restrict__ z,       // (B, 512, 512, 128)
    const float* __restrict__ Wb,      // (12, 128)
    const float* __restrict__ bbv,     // (12)
    const float* __restrict__ hwin,    // (12)
    const float* __restrict__ mask,    // (B, N)
    const float* __restrict__ rot,
    const float* __restrict__ trans,
    float* __restrict__ cat)           // (M, 2112)
{
    __shared__ float zn[KNB][CZP];     // 26.4 KB, padded rows
    __shared__ float WbS[HH][CZP];     // 6.3 KB
    __shared__ float aP[HH][KNB + 2];
    __shared__ float qloc[192];
    __shared__ float qp[144];
    __shared__ int   nk[KNB];
    __shared__ float maskn[KNB];
    __shared__ float hwS[HH];
    __shared__ float opt[288];

    const int m = blockIdx.x;
    const int b = m / NN, n = m % NN;
    const int tid = threadIdx.x;
    const int lane = tid & 63, wid = tid >> 6;

    if (tid < KNB) nk[tid] = nidx[(size_t)m * KNB + tid];
    __syncthreads();

    for (int i = tid; i < HH * CZD; i += 256) WbS[i / CZD][i % CZD] = Wb[i];
    for (int i = tid; i < 192; i += 256) qloc[i] = lin[(size_t)m * LINW + i];
    for (int i = tid; i < 144; i += 256) qp[i] = q_pts[(size_t)m * 144 + i];
    if (tid < HH) hwS[tid] = log1pf(expf(hwin[tid])) * 0.13608276348795434f; // sqrt(1/54)
    if (tid < KNB) maskn[tid] = 100000.0f * (mask[m] * mask[(size_t)b * NN + nk[tid]] - 1.0f);
    {
        // float4 z gather: each wave covers 2 rows/iter (32 lanes * float4 = 128 floats)
        const int sub = lane >> 5, l32 = lane & 31;
        for (int k = wid * 2 + sub; k < KNB; k += 8) {
            const float* zr = z + (((size_t)b * HALFN + (n & (HALFN-1))) * HALFN + (nk[k] & (HALFN-1))) * CZD;
            float4 v4 = *(const float4*)(zr + l32 * 4);
            *(float4*)&zn[k][l32 * 4] = v4;
        }
    }
    __syncthreads();

    // logits
    for (int idx = tid; idx < HH * KNB; idx += 256) {
        int k = idx / HH, h = idx % HH;
        int mk = b * NN + nk[k];
        const float* kvr = lin + (size_t)mk * LINW + 192 + h * 32;
        float qk = 0.f;
        #pragma unroll
        for (int c4 = 0; c4 < 4; ++c4) {
            float4 kv4 = *(const float4*)(kvr + c4 * 4);
            float4 q4  = *(const float4*)&qloc[h * 16 + c4 * 4];
            qk += q4.x*kv4.x + q4.y*kv4.y + q4.z*kv4.z + q4.w*kv4.w;
        }
        const float* kpr = k_pts + (size_t)mk * 144 + h * 12;
        float d2s = 0.f;
        #pragma unroll
        for (int p = 0; p < PQD; ++p) {
            float dx = qp[h*12 + p*3 + 0] - kpr[p*3 + 0];
            float dy = qp[h*12 + p*3 + 1] - kpr[p*3 + 1];
            float dz = qp[h*12 + p*3 + 2] - kpr[p*3 + 2];
            d2s += dx*dx + dy*dy + dz*dz;
        }
        float4 acc4 = {0.f, 0.f, 0.f, 0.f};
        #pragma unroll 8
        for (int c4 = 0; c4 < 32; ++c4) {
            float4 z4 = *(const float4*)&zn[k][c4 * 4];
            float4 w4 = *(const float4*)&WbS[h][c4 * 4];
            acc4.x += z4.x*w4.x; acc4.y += z4.y*w4.y;
            acc4.z += z4.z*w4.z; acc4.w += z4.w*w4.w;
        }
        float bp = bbv[h] + acc4.x + acc4.y + acc4.z + acc4.w;
        aP[h][k] = qk * 0.14433756729740643f      // sqrt(1/(3*16))
                 + 0.5773502691896258f * bp       // sqrt(1/3)
                 - 0.5f * hwS[h] * d2s
                 + maskn[k];
    }
    __syncthreads();

    // softmax over k per head (wave-parallel, lanes 0..49 hold values)
    for (int h = wid; h < HH; h += 4) {
        float v = (lane < KNB) ? aP[h][lane] : -1e30f;
        float mx = v;
        #pragma unroll
        for (int off = 32; off; off >>= 1) mx = fmaxf(mx, __shfl_xor(mx, off));
        float e = (lane < KNB) ? expf(v - mx) : 0.f;
        float s = e;
        #pragma unroll
        for (int off = 32; off; off >>= 1) s += __shfl_xor(s, off);
        if (lane < KNB) aP[h][lane] = e / s;
    }
    __syncthreads();

    // o (48 float4) and o_pt raw (72 float4)
    if (tid < 120) {
        float4 acc = {0.f, 0.f, 0.f, 0.f};
        if (tid < 48) {
            int h = tid >> 2, c4 = tid & 3;
            for (int k = 0; k < KNB; ++k) {
                int mk = b * NN + nk[k];
                float4 v4 = *(const float4*)(lin + (size_t)mk * LINW + 192 + h*32 + 16 + c4*4);
                float a = aP[h][k];
                acc.x += a*v4.x; acc.y += a*v4.y; acc.z += a*v4.z; acc.w += a*v4.w;
            }
            *(float4*)(cat + (size_t)m * CATW + tid * 4) = acc;
        } else {
            int u2 = tid - 48;                   // 0..71
            int h = (u2 * 4) / 24, r = (u2 * 4) % 24;
            for (int k = 0; k < KNB; ++k) {
                int mk = b * NN + nk[k];
                float4 v4 = *(const float4*)(v_pts + (size_t)mk * 288 + h*24 + r);
                float a = aP[h][k];
                acc.x += a*v4.x; acc.y += a*v4.y; acc.z += a*v4.z; acc.w += a*v4.w;
            }
            *(float4*)&opt[u2 * 4] = acc;
        }
    }
    __syncthreads();

    // inverse frame transform + norm
    if (tid < 96) {
        int hp = tid;
        float x = opt[hp*3+0] - trans[(size_t)m*3+0];
        float y = opt[hp*3+1] - trans[(size_t)m*3+1];
        float z0 = opt[hp*3+2] - trans[(size_t)m*3+2];
        const float* R = rot + (size_t)m * 9;
        float o0 = R[0]*x + R[3]*y + R[6]*z0;   // rot^T
        float o1 = R[1]*x + R[4]*y + R[7]*z0;
        float o2 = R[2]*x + R[5]*y + R[8]*z0;
        float nrm = sqrtf(o0*o0 + o1*o1 + o2*o2 + 1e-8f);
        float* c0 = cat + (size_t)m * CATW;
        c0[192 + hp] = o0;
        c0[288 + hp] = o1;
        c0[384 + hp] = o2;
        c0[480 + hp] = nrm;
    }

    // o_pair: 12 heads x 32 float4 columns from LDS zn
    for (int u = tid; u < HH * 32; u += 256) {
        int h = u >> 5, c4 = u & 31;
        float4 acc = {0.f, 0.f, 0.f, 0.f};
        for (int k = 0; k < KNB; ++k) {
            float a = aP[h][k];
            float4 z4 = *(const float4*)&zn[k][c4 * 4];
            acc.x += a*z4.x; acc.y += a*z4.y; acc.z += a*z4.z; acc.w += a*z4.w;
        }
        *(float4*)(cat + (size_t)m * CATW + 576 + h * 128 + c4 * 4) = acc;
    }
}

extern "C" void kernel_launch(void* const* d_in, const int* in_sizes, int n_in,
                              void* d_out, int out_size, void* d_ws, size_t ws_size,
                              hipStream_t stream) {
    const float* s     = (const float*)d_in[0];
    const float* z     = (const float*)d_in[1];
    const float* rot   = (const float*)d_in[2];
    const float* trans = (const float*)d_in[3];
    const float* mask  = (const float*)d_in[4];
    // d_in[5] rel_pos unused
    const float* Wq    = (const float*)d_in[6];
    const float* bq    = (const float*)d_in[7];
    const float* Wkv   = (const float*)d_in[8];
    const float* bkv   = (const float*)d_in[9];
    const float* Wqp   = (const float*)d_in[10];
    const float* bqp   = (const float*)d_in[11];
    const float* Wkvp  = (const float*)d_in[12];
    const float* bkvp  = (const float*)d_in[13];
    const float* Wb    = (const float*)d_in[14];
    const float* bb    = (const float*)d_in[15];
    const float* hw    = (const float*)d_in[16];
    const float* Wout  = (const float*)d_in[17];
    const float* bout  = (const float*)d_in[18];
    float* out = (float*)d_out;

    float* ws    = (float*)d_ws;
    float* lin   = ws;                              // 2048*1152
    float* qpts  = lin  + (size_t)MTOK * LINW;      // 2048*144
    float* kpts  = qpts + (size_t)MTOK * 144;       // 2048*144
    float* vpts  = kpts + (size_t)MTOK * 144;       // 2048*288
    int*   nidxb = (int*)(vpts + (size_t)MTOK * 288);
    float* cat   = (float*)(nidxb + (size_t)MTOK * KNB); // 2048*2112
    float* parts = cat + (size_t)MTOK * CATW;       // SPLITK * 2048*384

    dim3 g1(MTOK / 64, LINW / 64);
    proj_gemm<<<g1, 256, 0, stream>>>(s, Wq, bq, Wkv, bkv, Wqp, bqp, Wkvp, bkvp, lin);
    point_transform<<<MTOK, 192, 0, stream>>>(lin, rot, trans, qpts, kpts, vpts);
    topk_kernel<<<MTOK, 256, 0, stream>>>(trans, nidxb);
    attn_kernel<<<MTOK, 256, 0, stream>>>(lin, qpts, kpts, vpts, nidxb, z, Wb, bb, hw,
                                          mask, rot, trans, cat);
    dim3 g2(MTOK / 64, 384 / 64, SPLITK);
    gemm_wt_splitk<<<g2, 256, 0, stream>>>(cat, Wout, parts, CATW, 384, CATW / SPLITK);
    reduce_splitk<<<(MTOK * 384 / 4 + 255) / 256, 256, 0, stream>>>(parts, bout, out);
}